// Round 14
// baseline (225.440 us; speedup 1.0000x reference)
//
#include <hip/hip_runtime.h>
#include <math.h>

#define B 4
#define L 2048
#define D 256
#define POSP 16
#define LTMP 16
#define T 64
#define C 32
#define F 72
#define PI_F 3.14159274101257324f
#define TWO_PI_D 6.283185307179586476925286766559

// -- prep: pos phasors (interleaved) + Wt transpose + 16-row x/x^2 sums ----------
// grid 688: [0,128) pos, [128,176) Wt, [176,688) stats16 (512 = 128 s-chunks x B)
__global__ __launch_bounds__(256) void prep_kernel(const float* __restrict__ pos_freqs,
                                                   const float* __restrict__ lkp,
                                                   const float* __restrict__ x,
                                                   float* __restrict__ posci,
                                                   float* __restrict__ Wt,
                                                   float* __restrict__ Sx16,
                                                   float* __restrict__ Sxx16) {
    int bid = blockIdx.x;
    int tid = threadIdx.x;
    if (bid < 128) {
        int idx = bid * 256 + tid;
        int t = idx >> 4, p = idx & 15;
        float a = (float)t * pos_freqs[p];   // replicate numpy op order in fp32
        float th = (a * 2.0f) * PI_F;
        double r = fmod((double)th, TWO_PI_D);
        posci[t * 32 + 2 * p] = (float)cos(r);
        posci[t * 32 + 2 * p + 1] = (float)sin(r);
    } else if (bid < 176) {
        int i2 = (bid - 128) * 256 + tid;
        if (i2 < 16 * 768) {
            int p = i2 / 768, j = i2 - p * 768;
            Wt[i2] = lkp[j * 16 + p];
        }
    } else {
        int sb = bid - 176;          // 0..511
        int s = sb & 127, b = sb >> 7;
        float sx = 0.f, sxx = 0.f;
#pragma unroll
        for (int k = 0; k < 16; k++) {
            float v = x[((size_t)(b * L + s * 16 + k)) * D + tid];
            sx += v; sxx += v * v;
        }
        Sx16[((size_t)(b * 128 + s)) * D + tid] = sx;
        Sxx16[((size_t)(b * 128 + s)) * D + tid] = sxx;
    }
}

// ---------------- featurize: fused GEMM x @ [w_value | key_proj | query_proj] ---
__global__ __launch_bounds__(256) void featurize_kernel(
    const float* __restrict__ x, const float* __restrict__ key_proj,
    const float* __restrict__ query_proj, const float* __restrict__ w_value,
    const float* __restrict__ b_value, const float* __restrict__ set_weights,
    float* __restrict__ V, float* __restrict__ fk, float* __restrict__ fq,
    float* __restrict__ partial) {
    int cg = blockIdx.x;
    int rc = blockIdx.y;
    int b  = blockIdx.z;
    int row0 = rc * 64;
    int tid = threadIdx.x;
    __shared__ float xs[2][32][74];   // [buf][k][row] transposed x, stride 74
    __shared__ float ws[2][32][84];   // [buf][k][64 V-cols + 16 proj cols]
    __shared__ float zbuf[64][20];
    __shared__ float jkv[64][9];
    const bool has_proj = (cg < 2);
    const float* proj = (cg == 0) ? key_proj : query_proj;
    int rg = tid >> 4, cgi = tid & 15;
    int r0 = rg * 4, c0 = cgi * 4;
    int prow = tid >> 2, pc4 = tid & 3;
    float acc[4][4], accp[4];
#pragma unroll
    for (int i = 0; i < 4; i++) {
#pragma unroll
        for (int e = 0; e < 4; e++) acc[i][e] = 0.f;
        accp[i] = 0.f;
    }
    int rrA = tid >> 3, k4A = tid & 7;     // x stage mapping
    int jA = tid >> 4, c4A = tid & 15;     // w stage mapping
    float4 xr0, xr1, wr0, wr1, prr;

#define ISSUE_LOADS(kb_)                                                            \
    {                                                                               \
        xr0 = *(const float4*)(x + ((size_t)(b * L + row0 + rrA)) * D + (kb_) + k4A * 4);      \
        xr1 = *(const float4*)(x + ((size_t)(b * L + row0 + 32 + rrA)) * D + (kb_) + k4A * 4); \
        wr0 = *(const float4*)(w_value + (size_t)((kb_) + jA) * D + cg * 64 + c4A * 4);        \
        wr1 = *(const float4*)(w_value + (size_t)((kb_) + 16 + jA) * D + cg * 64 + c4A * 4);   \
        if (has_proj && tid < 128)                                                  \
            prr = *(const float4*)(proj + (size_t)((kb_) + (tid >> 2)) * 16 + (tid & 3) * 4);  \
    }
#define WRITE_LDS(bi)                                                               \
    {                                                                               \
        const float* xp0 = (const float*)&xr0;                                      \
        const float* xp1 = (const float*)&xr1;                                      \
        _Pragma("unroll")                                                           \
        for (int u = 0; u < 4; u++) {                                               \
            xs[bi][k4A * 4 + u][rrA] = xp0[u];                                      \
            xs[bi][k4A * 4 + u][32 + rrA] = xp1[u];                                 \
        }                                                                           \
        *(float4*)&ws[bi][jA][c4A * 4] = wr0;                                       \
        *(float4*)&ws[bi][16 + jA][c4A * 4] = wr1;                                  \
        if (has_proj && tid < 128)                                                  \
            *(float4*)&ws[bi][tid >> 2][64 + (tid & 3) * 4] = prr;                  \
    }

    ISSUE_LOADS(0);
    WRITE_LDS(0);
    __syncthreads();
    for (int kc = 0; kc < 8; kc++) {
        if (kc < 7) ISSUE_LOADS((kc + 1) * 32);
        int bi = kc & 1;
#pragma unroll 8
        for (int j = 0; j < 32; j++) {
            float2 xlo = *(float2*)&xs[bi][j][r0];
            float2 xhi = *(float2*)&xs[bi][j][r0 + 2];
            float4 wv = *(float4*)&ws[bi][j][c0];
            acc[0][0] += xlo.x * wv.x; acc[0][1] += xlo.x * wv.y; acc[0][2] += xlo.x * wv.z; acc[0][3] += xlo.x * wv.w;
            acc[1][0] += xlo.y * wv.x; acc[1][1] += xlo.y * wv.y; acc[1][2] += xlo.y * wv.z; acc[1][3] += xlo.y * wv.w;
            acc[2][0] += xhi.x * wv.x; acc[2][1] += xhi.x * wv.y; acc[2][2] += xhi.x * wv.z; acc[2][3] += xhi.x * wv.w;
            acc[3][0] += xhi.y * wv.x; acc[3][1] += xhi.y * wv.y; acc[3][2] += xhi.y * wv.z; acc[3][3] += xhi.y * wv.w;
            if (has_proj) {
                float xp = xs[bi][j][prow];
                float4 wp = *(float4*)&ws[bi][j][64 + pc4 * 4];
                accp[0] += xp * wp.x; accp[1] += xp * wp.y;
                accp[2] += xp * wp.z; accp[3] += xp * wp.w;
            }
        }
        if (kc < 7) WRITE_LDS((kc + 1) & 1);
        __syncthreads();
    }
#undef ISSUE_LOADS
#undef WRITE_LDS

    // V epilogue
    {
        int d0 = cg * 64 + c0;
        float4 bv = *(const float4*)(b_value + d0);
#pragma unroll
        for (int i = 0; i < 4; i++) {
            size_t o = ((size_t)(b * L + row0 + r0 + i)) * D + d0;
            *(float4*)(V + o) = make_float4(acc[i][0] + bv.x, acc[i][1] + bv.y,
                                            acc[i][2] + bv.z, acc[i][3] + bv.w);
        }
    }
    if (!has_proj) return;
#pragma unroll
    for (int e = 0; e < 4; e++) zbuf[prow][pc4 * 4 + e] = tanhf(accp[e]) * PI_F;
    __syncthreads();
    // phasor epilogue: 64 rows x 4 threads; thread handles 4 cols + joint plane q
    {
        int tt = tid >> 2, q = tid & 3;
        size_t bt = (size_t)(b * L + row0 + tt);
        if (cg == 0) {
            float* fp = fk + bt * 40;
#pragma unroll
            for (int e = 0; e < 4; e++) {
                int col = q * 4 + e;
                float si, co; sincosf(zbuf[tt][col], &si, &co);
                fp[2 * col] = co; fp[2 * col + 1] = si;
            }
            float zs = zbuf[tt][q] + zbuf[tt][4 + q] + zbuf[tt][8 + q] + zbuf[tt][12 + q];
            float si, co; sincosf(zs, &si, &co);
            fp[32 + 2 * q] = co; fp[33 + 2 * q] = si;
            jkv[tt][2 * q] = co; jkv[tt][2 * q + 1] = si;
        } else {
            float sw0 = set_weights[0], sw1 = set_weights[1], sw2 = set_weights[2], sw3 = set_weights[3];
            float mx = fmaxf(fmaxf(sw0, sw1), fmaxf(sw2, sw3));
            float e0 = expf(sw0 - mx), e1 = expf(sw1 - mx), e2 = expf(sw2 - mx), e3 = expf(sw3 - mx);
            float esum = e0 + e1 + e2 + e3;
            float wsoft[4] = {e0 / esum, e1 / esum, e2 / esum, e3 / esum};
            float* fp = fq + bt * 40;
#pragma unroll
            for (int e = 0; e < 4; e++) {
                int col = q * 4 + e;
                float si, co; sincosf(zbuf[tt][col], &si, &co);
                float sc = 0.1f * wsoft[col >> 2];   // 0.5 * w_s / (NSETS+1)
                fp[2 * col] = sc * co; fp[2 * col + 1] = sc * si;
            }
            float zs = zbuf[tt][q] + zbuf[tt][4 + q] + zbuf[tt][8 + q] + zbuf[tt][12 + q];
            float si, co; sincosf(zs, &si, &co);
            fp[32 + 2 * q] = 0.1f * co; fp[33 + 2 * q] = 0.1f * si;
        }
    }
    __syncthreads();
    if (cg == 0) {   // reduce ungated jk over two 32-row halves -> 2 chunk partials
        int h = tid >> 7, idxr = tid & 127;
        int rr2 = idxr >> 3, ch = idxr & 7;
#pragma unroll
        for (int s2 = 16; s2 >= 1; s2 >>= 1) {
            if (rr2 < s2) jkv[h * 32 + rr2][ch] += jkv[h * 32 + rr2 + s2][ch];
            __syncthreads();
        }
        if (rr2 == 0) partial[((size_t)(b * 64 + rc * 2 + h)) * 8 + ch] = jkv[h * 32][ch];
    }
}

// ---- gate apply (fused scan): per-block chunk offset + local scan + gate fk ----
// grid (64, B); threads 0..7 serially sum partials of chunks < rc (independent
// loads, tiny); then 32-row local scan; then gate & scale.
__global__ __launch_bounds__(256) void gs_apply_kernel(
    float* __restrict__ fk, const float* __restrict__ partial,
    const float* __restrict__ surprise_scale, const float* __restrict__ surprise_bias,
    const float* __restrict__ resonance_scale, const float* __restrict__ resonance_threshold) {
    int rc = blockIdx.x, b = blockIdx.y;
    int tid = threadIdx.x;
    int t = tid >> 3, ch = tid & 7;
    __shared__ float sc_[32][9];
    __shared__ float coff[8];
    __shared__ float gbuf[32];
    if (tid < 8) {
        float s = 0.f;
        const float* pp = partial + (size_t)b * 64 * 8 + tid;
        for (int c = 0; c < rc; c++) s += pp[c * 8];
        coff[tid] = s;
    }
    float* fp = fk + ((size_t)(b * L + rc * 32 + t)) * 40;
    float own = fp[32 + ch];
    sc_[t][ch] = own;
    __syncthreads();
    for (int off = 1; off < 32; off <<= 1) {
        float v = 0.f;
        if (t >= off) v = sc_[t - off][ch];
        __syncthreads();
        if (t >= off) sc_[t][ch] += v;
        __syncthreads();
    }
    float run = coff[ch] + sc_[t][ch] - own;
    __syncthreads();
    sc_[t][ch] = run;
    __syncthreads();
    if (tid < 32) {
        int tg = rc * 32 + tid;
        float r0 = sc_[tid][0], r1 = sc_[tid][1], r2 = sc_[tid][2], r3 = sc_[tid][3];
        float r4 = sc_[tid][4], r5 = sc_[tid][5], r6 = sc_[tid][6], r7 = sc_[tid][7];
        float rmag = 0.25f * (sqrtf(r0 * r0 + r1 * r1) + sqrtf(r2 * r2 + r3 * r3) +
                              sqrtf(r4 * r4 + r5 * r5) + sqrtf(r6 * r6 + r7 * r7));
        float scv = fminf(fmaxf(resonance_scale[0], 1.f), 20.f);
        float thv = fminf(fmaxf(resonance_threshold[0], 0.1f), 0.9f);
        float nres = rmag / sqrtf(fmaxf((float)tg, 1.0f));
        float surprise = 0.5f * (1.0f - tanhf(scv * (nres - thv)));
        gbuf[tid] = 1.0f / (1.0f + expf(-(surprise_scale[0] * (surprise - 0.5f) + surprise_bias[0])));
    }
    __syncthreads();
    float gv = gbuf[t];
#pragma unroll
    for (int e = 0; e < 5; e++) fp[ch * 5 + e] *= gv;
}

// ---------------- LTM phasor angles, 16 rows per block --------------------------
__global__ __launch_bounds__(256) void ltm_z_kernel(
    const float* __restrict__ x, const float* __restrict__ Sx16,
    const float* __restrict__ Sxx16, const float* __restrict__ Wt,
    float* __restrict__ czsz) {
    int s = blockIdx.x, b = blockIdx.y;
    int tid = threadIdx.x;
    __shared__ float xs[16][260], rms[16][260], rss[16][260];
    float a0 = 0.f, a1 = 0.f, a2 = 0.f, a3 = 0.f;
    float c0 = 0.f, c1 = 0.f, c2 = 0.f, c3 = 0.f;
    int sp = 0;
    for (; sp + 4 <= s; sp += 4) {
        a0 += Sx16[((size_t)(b * 128 + sp)) * D + tid];
        a1 += Sx16[((size_t)(b * 128 + sp + 1)) * D + tid];
        a2 += Sx16[((size_t)(b * 128 + sp + 2)) * D + tid];
        a3 += Sx16[((size_t)(b * 128 + sp + 3)) * D + tid];
        c0 += Sxx16[((size_t)(b * 128 + sp)) * D + tid];
        c1 += Sxx16[((size_t)(b * 128 + sp + 1)) * D + tid];
        c2 += Sxx16[((size_t)(b * 128 + sp + 2)) * D + tid];
        c3 += Sxx16[((size_t)(b * 128 + sp + 3)) * D + tid];
    }
    for (; sp < s; sp++) {
        a0 += Sx16[((size_t)(b * 128 + sp)) * D + tid];
        c0 += Sxx16[((size_t)(b * 128 + sp)) * D + tid];
    }
    float runx = (a0 + a1) + (a2 + a3), runxx = (c0 + c1) + (c2 + c3);
    for (int k = 0; k < 16; k++) {
        int tg = s * 16 + k;
        float xv = x[((size_t)(b * L + tg)) * D + tid];
        runx += xv; runxx += xv * xv;
        float n = (float)(tg + 1);
        float rm = runx / n;
        float rv = runxx / n - rm * rm;
        xs[k][tid] = xv; rms[k][tid] = rm;
        rss[k][tid] = sqrtf(fmaxf(rv, 1e-8f));
    }
    __syncthreads();
    int tl = tid & 15, p = tid >> 4;
    const float* W0 = Wt + p * 768;
    float u0 = 0.f, u1 = 0.f, u2 = 0.f;
#pragma unroll 4
    for (int j4 = 0; j4 < 64; j4++) {
        float4 xv = *(float4*)&xs[tl][j4 * 4];
        float4 wx = *(const float4*)(W0 + j4 * 4);
        float4 rv = *(float4*)&rms[tl][j4 * 4];
        float4 wr = *(const float4*)(W0 + 256 + j4 * 4);
        float4 sv = *(float4*)&rss[tl][j4 * 4];
        float4 wz = *(const float4*)(W0 + 512 + j4 * 4);
        u0 += xv.x * wx.x + xv.y * wx.y + xv.z * wx.z + xv.w * wx.w;
        u1 += rv.x * wr.x + rv.y * wr.y + rv.z * wr.z + rv.w * wr.w;
        u2 += sv.x * wz.x + sv.y * wz.y + sv.z * wz.z + sv.w * wz.w;
    }
    float z = tanhf(u0 + u1 + u2) * PI_F;
    float si, co; sincosf(z, &si, &co);
    int tg = s * 16 + tl;
    czsz[((size_t)(b * L + tg)) * 32 + p] = co;
    czsz[((size_t)(b * L + tg)) * 32 + 16 + p] = si;
}

// ------------- half-chunk outer-product sums Sh[b,c,h,f,d] (32-t halves) --------
__global__ __launch_bounds__(256) void outer_sums_kernel(
    const float* __restrict__ V, const float* __restrict__ fk,
    const float* __restrict__ posci, float* __restrict__ Sh) {
    int g = blockIdx.x >> 1, h = blockIdx.x & 1;
    int c = blockIdx.y;
    int b = blockIdx.z;
    int tid = threadIdx.x;
    __shared__ float Fk[32][40];
    int F0 = g * 36;
#pragma unroll
    for (int e = 0; e < 2; e++) {
        int idx = e * 256 + tid;     // 288 f4 = 32 rows x 9
        if (idx < 288) {
            int r = idx / 9, c4 = idx - r * 9;
            int tg = c * T + h * 32 + r;
            float4 v;
            if (g == 0) v = *(const float4*)(fk + ((size_t)(b * L + tg)) * 40 + c4 * 4);
            else if (c4 == 0) v = *(const float4*)(fk + ((size_t)(b * L + tg)) * 40 + 36);
            else v = *(const float4*)(posci + tg * 32 + (c4 - 1) * 4);
            *(float4*)&Fk[r][c4 * 4] = v;
        }
    }
    __syncthreads();
    float acc[36];
#pragma unroll
    for (int f = 0; f < 36; f++) acc[f] = 0.f;
    for (int t = 0; t < 32; t++) {
        float v = V[((size_t)(b * L + c * T + h * 32 + t)) * D + tid];
#pragma unroll
        for (int f4 = 0; f4 < 9; f4++) {
            float4 fkv = *(float4*)&Fk[t][f4 * 4];
            acc[f4 * 4 + 0] += fkv.x * v;
            acc[f4 * 4 + 1] += fkv.y * v;
            acc[f4 * 4 + 2] += fkv.z * v;
            acc[f4 * 4 + 3] += fkv.w * v;
        }
    }
    for (int f = 0; f < 36; f++)
        Sh[((((size_t)(b * C + c)) * 2 + h) * F + F0 + f) * D + tid] = acc[f];
}

// ------- exclusive prefix over chunks, combining half-chunk sums ---------------
__global__ __launch_bounds__(256) void prefix_kernel(const float* __restrict__ Sh,
                                                     float* __restrict__ S) {
    int bf = blockIdx.x;
    int b = bf / F, f = bf % F;
    int d = threadIdx.x;
    float v0[C], v1[C];
#pragma unroll
    for (int c = 0; c < C; c++) {
        v0[c] = Sh[((((size_t)(b * C + c)) * 2 + 0) * F + f) * D + d];
        v1[c] = Sh[((((size_t)(b * C + c)) * 2 + 1) * F + f) * D + d];
    }
    float run = 0.f;
#pragma unroll
    for (int c = 0; c < C; c++) {
        S[(((size_t)(b * C + c)) * F + f) * D + d] = run;
        run += v0[c] + v1[c];
    }
}

// ---- intra fused w/ hprep, 512 threads: hn = LN((Fq·M + A·V + pers)/nrm)·g + b --
__global__ __launch_bounds__(512) void intra_kernel(
    const float* __restrict__ V, float* __restrict__ hn,
    const float* __restrict__ fk, const float* __restrict__ fq,
    const float* __restrict__ posci, const float* __restrict__ Mexc,
    const float* __restrict__ pos_weight, const float* __restrict__ czsz,
    const float* __restrict__ ltm_mem, const float* __restrict__ ltm_count,
    const float* __restrict__ ltm_weight, const float* __restrict__ ln_gamma,
    const float* __restrict__ ln_beta) {
    int tg = blockIdx.x, c = blockIdx.y, b = blockIdx.z;
    int tid = threadIdx.x;
    int t0 = tg * 16;
    __shared__ float smem[8384];
    float (*Fk)[76] = (float(*)[76])smem;              // 64*76 = 4864
    float (*Fq)[76] = (float(*)[76])(smem + 4864);     // 16*76 -> 6080
    float (*As)[68] = (float(*)[68])(smem + 6080);     // 16*68 -> 7168
    float (*cs)[33]  = (float(*)[33])(smem + 7168);    // 528 -> 7696
    float (*part1)[17] = (float(*)[17])(smem + 7696);  // 272 -> 7968
    float (*part2)[17] = (float(*)[17])(smem + 7968);  // 272 -> 8240
    float* mu   = smem + 8240;
    float* rsig = smem + 8256;
    float (*hb)[260] = (float(*)[260])smem;            // aliases Fk (4160 <= 4864)
    float posq = 0.5f / (1.0f + expf(-pos_weight[0]));
    // stage Fk: 64 rows x 18 f4 (10 from fk, 8 from posci)
#pragma unroll
    for (int e = 0; e < 3; e++) {
        int idx = e * 512 + tid;
        if (idx < 1152) {
            int r = idx / 18, c4 = idx - r * 18;
            int tgl = c * T + r;
            float4 v;
            if (c4 < 10) v = *(const float4*)(fk + ((size_t)(b * L + tgl)) * 40 + c4 * 4);
            else v = *(const float4*)(posci + tgl * 32 + (c4 - 10) * 4);
            *(float4*)&Fk[r][c4 * 4] = v;
        }
    }
    // stage Fq: 16 rows x 18 f4; pos part scaled by posq
    if (tid < 288) {
        int r = tid / 18, c4 = tid - r * 18;
        int tgl = c * T + t0 + r;
        float4 v;
        if (c4 < 10) v = *(const float4*)(fq + ((size_t)(b * L + tgl)) * 40 + c4 * 4);
        else {
            v = *(const float4*)(posci + tgl * 32 + (c4 - 10) * 4);
            v.x *= posq; v.y *= posq; v.z *= posq; v.w *= posq;
        }
        *(float4*)&Fq[r][c4 * 4] = v;
    }
    // stage czsz: 512 = 16 rows x 32
    {
        int t = tid >> 5, q = tid & 31;
        cs[t][q] = czsz[((size_t)(b * L + c * T + t0 + t)) * 32 + q];
    }
    __syncthreads();
    // A[r][k]: 16 x 64; thread handles k = kA and kA+32 for row r (computed ONCE)
    {
        int r = tid >> 5, kA = tid & 31;
        int tglob = t0 + r;
        float a0 = 0.f, a1 = 0.f;
#pragma unroll
        for (int f4 = 0; f4 < 18; f4++) {
            float4 q = *(float4*)&Fq[r][f4 * 4];
            float4 kv0 = *(float4*)&Fk[kA][f4 * 4];
            float4 kv1 = *(float4*)&Fk[kA + 32][f4 * 4];
            a0 += q.x * kv0.x + q.y * kv0.y + q.z * kv0.z + q.w * kv0.w;
            a1 += q.x * kv1.x + q.y * kv1.y + q.z * kv1.z + q.w * kv1.w;
        }
        As[r][kA] = (kA <= tglob) ? a0 : 0.f;
        As[r][kA + 32] = (kA + 32 <= tglob) ? a1 : 0.f;
    }
    __syncthreads();   // Fk retired; region may be reused as hb
    // main: thread owns column d = tid&255, rows r0..r0+7 (r0 = (tid>>8)*8)
    int d = tid & 255, half = tid >> 8;
    int r0 = half * 8;
    float acc[8];
#pragma unroll
    for (int i = 0; i < 8; i++) acc[i] = 0.f;
    const float* Mp = Mexc + (((size_t)(b * C + c)) * F) * D + d;
#pragma unroll 8
    for (int f = 0; f < F; f++) {
        float m = Mp[(size_t)f * D];
#pragma unroll
        for (int i = 0; i < 8; i++) acc[i] += Fq[r0 + i][f] * m;
    }
    const float* Vp = V + ((size_t)(b * L + c * T)) * D + d;
    int kmax = t0 + r0 + 8;        // causality: rows r0..r0+7 need k <= t0+r0+7
#pragma unroll 8
    for (int k = 0; k < kmax; k++) {
        float v = Vp[(size_t)k * D];
#pragma unroll
        for (int i = 0; i < 8; i++) acc[i] += As[r0 + i][k] * v;
    }
    // + LTM pers, /nrm
    float lsig = 1.f / (1.f + expf(-ltm_weight[0]));
    float pnorm = sqrtf(fmaxf(ltm_count[0], 1.f) * (float)LTMP);
    float lcoef = lsig / pnorm;
    float Mre[16], Mim[16];
#pragma unroll
    for (int p = 0; p < 16; p++) {
        Mre[p] = ltm_mem[(p * D + d) * 2];
        Mim[p] = ltm_mem[(p * D + d) * 2 + 1];
    }
#pragma unroll
    for (int i = 0; i < 8; i++) {
        int row = r0 + i;
        float pers = 0.f;
#pragma unroll
        for (int p = 0; p < 16; p++) pers += Mre[p] * cs[row][p] + Mim[p] * cs[row][16 + p];
        int tgl = c * T + t0 + row;
        acc[i] = (acc[i] + lcoef * pers) / (2.0f * sqrtf((float)(tgl + 1)));
    }
    __syncthreads();   // all As/Fq/cs reads done before hb overwrite of Fk region
#pragma unroll
    for (int i = 0; i < 8; i++) hb[r0 + i][d] = acc[i];
    __syncthreads();
    // LN stats (tid<256): row = tid&15, e = tid>>4; cols e+16k -> 2-way banks
    if (tid < 256) {
        int row = tid & 15, e = tid >> 4;
        float s1 = 0.f, s2 = 0.f;
#pragma unroll
        for (int k = 0; k < 16; k++) {
            float v = hb[row][e + 16 * k];
            s1 += v; s2 += v * v;
        }
        part1[row][e] = s1; part2[row][e] = s2;
    }
    __syncthreads();
    if (tid < 16) {
        float s1 = 0.f, s2 = 0.f;
#pragma unroll
        for (int e = 0; e < 16; e++) { s1 += part1[tid][e]; s2 += part2[tid][e]; }
        float m = s1 / 256.f;
        mu[tid] = m;
        rsig[tid] = rsqrtf(fmaxf(s2 / 256.f - m * m, 0.f) + 1e-5f);
    }
    __syncthreads();
    float gam = ln_gamma[d], bet = ln_beta[d];
#pragma unroll
    for (int i = 0; i < 8; i++) {
        int row = r0 + i;
        hn[((size_t)(b * L + c * T + t0 + row)) * D + d] =
            (acc[i] - mu[row]) * rsig[row] * gam + bet;
    }
}

// ---------------- gemm_out: out = x + hn @ w_out + b_out ------------------------
__global__ __launch_bounds__(256) void gemm_out_kernel(
    const float* __restrict__ hn, const float* __restrict__ w_out,
    const float* __restrict__ b_out, const float* __restrict__ x,
    float* __restrict__ out) {
    int cg = blockIdx.x;
    int rc = blockIdx.y;
    int b  = blockIdx.z;
    int row0 = rc * 64;
    int tid = threadIdx.x;
    __shared__ float hs[2][32][74];
    __shared__ float wo[2][32][68];
    int rg = tid >> 4, cgi = tid & 15;
    int r0 = rg * 4, c0 = cgi * 4;
    float acc[4][4];
#pragma unroll
    for (int i = 0; i < 4; i++)
#pragma unroll
        for (int e = 0; e < 4; e++) acc[i][e] = 0.f;
    int rrA = tid >> 3, k4A = tid & 7;
    int jA = tid >> 4, c4A = tid & 15;
    float4 hr0, hr1, wr0, wr1;

#define ISSUE_LOADS(kb_)                                                            \
    {                                                                               \
        hr0 = *(const float4*)(hn + ((size_t)(b * L + row0 + rrA)) * D + (kb_) + k4A * 4);      \
        hr1 = *(const float4*)(hn + ((size_t)(b * L + row0 + 32 + rrA)) * D + (kb_) + k4A * 4); \
        wr0 = *(const float4*)(w_out + (size_t)((kb_) + jA) * D + cg * 64 + c4A * 4);           \
        wr1 = *(const float4*)(w_out + (size_t)((kb_) + 16 + jA) * D + cg * 64 + c4A * 4);      \
    }
#define WRITE_LDS(bi)                                                               \
    {                                                                               \
        const float* hp0 = (const float*)&hr0;                                      \
        const float* hp1 = (const float*)&hr1;                                      \
        _Pragma("unroll")                                                           \
        for (int u = 0; u < 4; u++) {                                               \
            hs[bi][k4A * 4 + u][rrA] = hp0[u];                                      \
            hs[bi][k4A * 4 + u][32 + rrA] = hp1[u];                                 \
        }                                                                           \
        *(float4*)&wo[bi][jA][c4A * 4] = wr0;                                       \
        *(float4*)&wo[bi][16 + jA][c4A * 4] = wr1;                                  \
    }

    ISSUE_LOADS(0);
    WRITE_LDS(0);
    __syncthreads();
    for (int kc = 0; kc < 8; kc++) {
        if (kc < 7) ISSUE_LOADS((kc + 1) * 32);
        int bi = kc & 1;
#pragma unroll 8
        for (int j = 0; j < 32; j++) {
            float2 xlo = *(float2*)&hs[bi][j][r0];
            float2 xhi = *(float2*)&hs[bi][j][r0 + 2];
            float4 wv = *(float4*)&wo[bi][j][c0];
            acc[0][0] += xlo.x * wv.x; acc[0][1] += xlo.x * wv.y; acc[0][2] += xlo.x * wv.z; acc[0][3] += xlo.x * wv.w;
            acc[1][0] += xlo.y * wv.x; acc[1][1] += xlo.y * wv.y; acc[1][2] += xlo.y * wv.z; acc[1][3] += xlo.y * wv.w;
            acc[2][0] += xhi.x * wv.x; acc[2][1] += xhi.x * wv.y; acc[2][2] += xhi.x * wv.z; acc[2][3] += xhi.x * wv.w;
            acc[3][0] += xhi.y * wv.x; acc[3][1] += xhi.y * wv.y; acc[3][2] += xhi.y * wv.z; acc[3][3] += xhi.y * wv.w;
        }
        if (kc < 7) WRITE_LDS((kc + 1) & 1);
        __syncthreads();
    }
#undef ISSUE_LOADS
#undef WRITE_LDS
    {
        int d0 = cg * 64 + c0;
        float4 bo = *(const float4*)(b_out + d0);
#pragma unroll
        for (int i = 0; i < 4; i++) {
            size_t o = ((size_t)(b * L + row0 + r0 + i)) * D + d0;
            float4 xa = *(const float4*)(x + o);
            *(float4*)(out + o) = make_float4(xa.x + acc[i][0] + bo.x, xa.y + acc[i][1] + bo.y,
                                              xa.z + acc[i][2] + bo.z, xa.w + acc[i][3] + bo.w);
        }
    }
}

extern "C" void kernel_launch(void* const* d_in, const int* in_sizes, int n_in,
                              void* d_out, int out_size, void* d_ws, size_t ws_size,
                              hipStream_t stream) {
    (void)in_sizes; (void)n_in; (void)out_size; (void)ws_size;
    const float* x            = (const float*)d_in[0];
    const float* key_proj     = (const float*)d_in[1];
    const float* query_proj   = (const float*)d_in[2];
    const float* ltm_key_proj = (const float*)d_in[3];
    const float* pos_freqs    = (const float*)d_in[4];
    const float* w_value      = (const float*)d_in[5];
    const float* b_value      = (const float*)d_in[6];
    const float* ln_gamma     = (const float*)d_in[9];
    const float* ln_beta      = (const float*)d_in[10];
    const float* w_out        = (const float*)d_in[11];
    const float* b_out        = (const float*)d_in[12];
    const float* set_weights  = (const float*)d_in[13];
    const float* pos_weight   = (const float*)d_in[14];
    const float* surprise_scale      = (const float*)d_in[15];
    const float* surprise_bias       = (const float*)d_in[16];
    const float* resonance_scale     = (const float*)d_in[17];
    const float* resonance_threshold = (const float*)d_in[18];
    const float* ltm_weight   = (const float*)d_in[19];
    const float* ltm_mem      = (const float*)d_in[20];
    const float* ltm_count    = (const float*)d_in[21];
    float* out = (float*)d_out;

    float* ws = (float*)d_ws;
    size_t off = 0;
    float* V     = ws + off; off += (size_t)B * L * D;
    float* hn    = ws + off; off += (size_t)B * L * D;   // intra writes hn directly
    float* fk    = ws + off; off += (size_t)B * L * 40;
    float* fq    = ws + off; off += (size_t)B * L * 40;
    float* posci = ws + off; off += (size_t)L * 32;
    float* Sx16  = ws + off; off += (size_t)B * 128 * D;
    float* Sxx16 = ws + off; off += (size_t)B * 128 * D;
    float* czsz  = ws + off; off += (size_t)B * L * 32;
    float* Sh    = ws + off; off += (size_t)B * C * 2 * F * D;   // half-chunk sums
    float* S     = ws + off; off += (size_t)B * C * F * D;       // exclusive prefix
    float* Wt    = ws + off; off += (size_t)16 * 768;
    float* partial = ws + off; off += (size_t)B * 64 * 8;

    prep_kernel<<<dim3(688), 256, 0, stream>>>(pos_freqs, ltm_key_proj, x, posci, Wt,
                                               Sx16, Sxx16);
    featurize_kernel<<<dim3(4, 32, B), 256, 0, stream>>>(x, key_proj, query_proj, w_value,
                                                         b_value, set_weights, V, fk, fq, partial);
    gs_apply_kernel<<<dim3(64, B), 256, 0, stream>>>(fk, partial, surprise_scale, surprise_bias,
                                                     resonance_scale, resonance_threshold);
    ltm_z_kernel<<<dim3(128, B), 256, 0, stream>>>(x, Sx16, Sxx16, Wt, czsz);
    outer_sums_kernel<<<dim3(4, C, B), 256, 0, stream>>>(V, fk, posci, Sh);
    prefix_kernel<<<dim3(B * F), 256, 0, stream>>>(Sh, S);
    intra_kernel<<<dim3(4, C, B), 512, 0, stream>>>(V, hn, fk, fq, posci, S, pos_weight,
                                                    czsz, ltm_mem, ltm_count, ltm_weight,
                                                    ln_gamma, ln_beta);
    gemm_out_kernel<<<dim3(4, 32, B), 256, 0, stream>>>(hn, w_out, b_out, x, out);
}

// Round 15
// 217.234 us; speedup vs baseline: 1.0378x; 1.0378x over previous
//
#include <hip/hip_runtime.h>
#include <math.h>

#define B 4
#define L 2048
#define D 256
#define POSP 16
#define LTMP 16
#define T 64
#define C 32
#define F 72
#define PI_F 3.14159274101257324f
#define TWO_PI_D 6.283185307179586476925286766559

// -- prep: pos phasors (interleaved) + Wt transpose + 16-row x/x^2 sums ----------
// grid 688: [0,128) pos, [128,176) Wt, [176,688) stats16 (512 = 128 s-chunks x B)
__global__ __launch_bounds__(256) void prep_kernel(const float* __restrict__ pos_freqs,
                                                   const float* __restrict__ lkp,
                                                   const float* __restrict__ x,
                                                   float* __restrict__ posci,
                                                   float* __restrict__ Wt,
                                                   float* __restrict__ Sx16,
                                                   float* __restrict__ Sxx16) {
    int bid = blockIdx.x;
    int tid = threadIdx.x;
    if (bid < 128) {
        int idx = bid * 256 + tid;
        int t = idx >> 4, p = idx & 15;
        float a = (float)t * pos_freqs[p];   // replicate numpy op order in fp32
        float th = (a * 2.0f) * PI_F;
        double r = fmod((double)th, TWO_PI_D);
        posci[t * 32 + 2 * p] = (float)cos(r);
        posci[t * 32 + 2 * p + 1] = (float)sin(r);
    } else if (bid < 176) {
        int i2 = (bid - 128) * 256 + tid;
        if (i2 < 16 * 768) {
            int p = i2 / 768, j = i2 - p * 768;
            Wt[i2] = lkp[j * 16 + p];
        }
    } else {
        int sb = bid - 176;          // 0..511
        int s = sb & 127, b = sb >> 7;
        float sx = 0.f, sxx = 0.f;
#pragma unroll
        for (int k = 0; k < 16; k++) {
            float v = x[((size_t)(b * L + s * 16 + k)) * D + tid];
            sx += v; sxx += v * v;
        }
        Sx16[((size_t)(b * 128 + s)) * D + tid] = sx;
        Sxx16[((size_t)(b * 128 + s)) * D + tid] = sxx;
    }
}

// ---------------- featurize: fused GEMM x @ [w_value | key_proj | query_proj] ---
__global__ __launch_bounds__(256) void featurize_kernel(
    const float* __restrict__ x, const float* __restrict__ key_proj,
    const float* __restrict__ query_proj, const float* __restrict__ w_value,
    const float* __restrict__ b_value, const float* __restrict__ set_weights,
    float* __restrict__ V, float* __restrict__ fk, float* __restrict__ fq,
    float* __restrict__ partial) {
    int cg = blockIdx.x;
    int rc = blockIdx.y;
    int b  = blockIdx.z;
    int row0 = rc * 64;
    int tid = threadIdx.x;
    __shared__ float xs[2][32][74];   // [buf][k][row] transposed x, stride 74
    __shared__ float ws[2][32][84];   // [buf][k][64 V-cols + 16 proj cols]
    __shared__ float zbuf[64][20];
    __shared__ float jkv[64][9];
    const bool has_proj = (cg < 2);
    const float* proj = (cg == 0) ? key_proj : query_proj;
    int rg = tid >> 4, cgi = tid & 15;
    int r0 = rg * 4, c0 = cgi * 4;
    int prow = tid >> 2, pc4 = tid & 3;
    float acc[4][4], accp[4];
#pragma unroll
    for (int i = 0; i < 4; i++) {
#pragma unroll
        for (int e = 0; e < 4; e++) acc[i][e] = 0.f;
        accp[i] = 0.f;
    }
    int rrA = tid >> 3, k4A = tid & 7;     // x stage mapping
    int jA = tid >> 4, c4A = tid & 15;     // w stage mapping
    float4 xr0, xr1, wr0, wr1, prr;

#define ISSUE_LOADS(kb_)                                                            \
    {                                                                               \
        xr0 = *(const float4*)(x + ((size_t)(b * L + row0 + rrA)) * D + (kb_) + k4A * 4);      \
        xr1 = *(const float4*)(x + ((size_t)(b * L + row0 + 32 + rrA)) * D + (kb_) + k4A * 4); \
        wr0 = *(const float4*)(w_value + (size_t)((kb_) + jA) * D + cg * 64 + c4A * 4);        \
        wr1 = *(const float4*)(w_value + (size_t)((kb_) + 16 + jA) * D + cg * 64 + c4A * 4);   \
        if (has_proj && tid < 128)                                                  \
            prr = *(const float4*)(proj + (size_t)((kb_) + (tid >> 2)) * 16 + (tid & 3) * 4);  \
    }
#define WRITE_LDS(bi)                                                               \
    {                                                                               \
        const float* xp0 = (const float*)&xr0;                                      \
        const float* xp1 = (const float*)&xr1;                                      \
        _Pragma("unroll")                                                           \
        for (int u = 0; u < 4; u++) {                                               \
            xs[bi][k4A * 4 + u][rrA] = xp0[u];                                      \
            xs[bi][k4A * 4 + u][32 + rrA] = xp1[u];                                 \
        }                                                                           \
        *(float4*)&ws[bi][jA][c4A * 4] = wr0;                                       \
        *(float4*)&ws[bi][16 + jA][c4A * 4] = wr1;                                  \
        if (has_proj && tid < 128)                                                  \
            *(float4*)&ws[bi][tid >> 2][64 + (tid & 3) * 4] = prr;                  \
    }

    ISSUE_LOADS(0);
    WRITE_LDS(0);
    __syncthreads();
    for (int kc = 0; kc < 8; kc++) {
        if (kc < 7) ISSUE_LOADS((kc + 1) * 32);
        int bi = kc & 1;
#pragma unroll 8
        for (int j = 0; j < 32; j++) {
            float2 xlo = *(float2*)&xs[bi][j][r0];
            float2 xhi = *(float2*)&xs[bi][j][r0 + 2];
            float4 wv = *(float4*)&ws[bi][j][c0];
            acc[0][0] += xlo.x * wv.x; acc[0][1] += xlo.x * wv.y; acc[0][2] += xlo.x * wv.z; acc[0][3] += xlo.x * wv.w;
            acc[1][0] += xlo.y * wv.x; acc[1][1] += xlo.y * wv.y; acc[1][2] += xlo.y * wv.z; acc[1][3] += xlo.y * wv.w;
            acc[2][0] += xhi.x * wv.x; acc[2][1] += xhi.x * wv.y; acc[2][2] += xhi.x * wv.z; acc[2][3] += xhi.x * wv.w;
            acc[3][0] += xhi.y * wv.x; acc[3][1] += xhi.y * wv.y; acc[3][2] += xhi.y * wv.z; acc[3][3] += xhi.y * wv.w;
            if (has_proj) {
                float xp = xs[bi][j][prow];
                float4 wp = *(float4*)&ws[bi][j][64 + pc4 * 4];
                accp[0] += xp * wp.x; accp[1] += xp * wp.y;
                accp[2] += xp * wp.z; accp[3] += xp * wp.w;
            }
        }
        if (kc < 7) WRITE_LDS((kc + 1) & 1);
        __syncthreads();
    }
#undef ISSUE_LOADS
#undef WRITE_LDS

    // V epilogue
    {
        int d0 = cg * 64 + c0;
        float4 bv = *(const float4*)(b_value + d0);
#pragma unroll
        for (int i = 0; i < 4; i++) {
            size_t o = ((size_t)(b * L + row0 + r0 + i)) * D + d0;
            *(float4*)(V + o) = make_float4(acc[i][0] + bv.x, acc[i][1] + bv.y,
                                            acc[i][2] + bv.z, acc[i][3] + bv.w);
        }
    }
    if (!has_proj) return;
#pragma unroll
    for (int e = 0; e < 4; e++) zbuf[prow][pc4 * 4 + e] = tanhf(accp[e]) * PI_F;
    __syncthreads();
    // phasor epilogue: 64 rows x 4 threads; thread handles 4 cols + joint plane q
    {
        int tt = tid >> 2, q = tid & 3;
        size_t bt = (size_t)(b * L + row0 + tt);
        if (cg == 0) {
            float* fp = fk + bt * 40;
#pragma unroll
            for (int e = 0; e < 4; e++) {
                int col = q * 4 + e;
                float si, co; sincosf(zbuf[tt][col], &si, &co);
                fp[2 * col] = co; fp[2 * col + 1] = si;
            }
            float zs = zbuf[tt][q] + zbuf[tt][4 + q] + zbuf[tt][8 + q] + zbuf[tt][12 + q];
            float si, co; sincosf(zs, &si, &co);
            fp[32 + 2 * q] = co; fp[33 + 2 * q] = si;
            jkv[tt][2 * q] = co; jkv[tt][2 * q + 1] = si;
        } else {
            float sw0 = set_weights[0], sw1 = set_weights[1], sw2 = set_weights[2], sw3 = set_weights[3];
            float mx = fmaxf(fmaxf(sw0, sw1), fmaxf(sw2, sw3));
            float e0 = expf(sw0 - mx), e1 = expf(sw1 - mx), e2 = expf(sw2 - mx), e3 = expf(sw3 - mx);
            float esum = e0 + e1 + e2 + e3;
            float wsoft[4] = {e0 / esum, e1 / esum, e2 / esum, e3 / esum};
            float* fp = fq + bt * 40;
#pragma unroll
            for (int e = 0; e < 4; e++) {
                int col = q * 4 + e;
                float si, co; sincosf(zbuf[tt][col], &si, &co);
                float sc = 0.1f * wsoft[col >> 2];   // 0.5 * w_s / (NSETS+1)
                fp[2 * col] = sc * co; fp[2 * col + 1] = sc * si;
            }
            float zs = zbuf[tt][q] + zbuf[tt][4 + q] + zbuf[tt][8 + q] + zbuf[tt][12 + q];
            float si, co; sincosf(zs, &si, &co);
            fp[32 + 2 * q] = 0.1f * co; fp[33 + 2 * q] = 0.1f * si;
        }
    }
    __syncthreads();
    if (cg == 0) {   // reduce ungated jk over two 32-row halves -> 2 chunk partials
        int h = tid >> 7, idxr = tid & 127;
        int rr2 = idxr >> 3, ch = idxr & 7;
#pragma unroll
        for (int s2 = 16; s2 >= 1; s2 >>= 1) {
            if (rr2 < s2) jkv[h * 32 + rr2][ch] += jkv[h * 32 + rr2 + s2][ch];
            __syncthreads();
        }
        if (rr2 == 0) partial[((size_t)(b * 64 + rc * 2 + h)) * 8 + ch] = jkv[h * 32][ch];
    }
}

// ---- mid: fused gate-apply [bid<64] + ltm_z [bid>=64] (same dependency level) --
// grid (192, B); 256 threads.
__global__ __launch_bounds__(256) void mid_kernel(
    float* __restrict__ fk, const float* __restrict__ partial,
    const float* __restrict__ surprise_scale, const float* __restrict__ surprise_bias,
    const float* __restrict__ resonance_scale, const float* __restrict__ resonance_threshold,
    const float* __restrict__ x, const float* __restrict__ Sx16,
    const float* __restrict__ Sxx16, const float* __restrict__ Wt,
    float* __restrict__ czsz) {
    int bid = blockIdx.x, b = blockIdx.y;
    int tid = threadIdx.x;
    if (bid < 64) {
        // ---------------- gate apply ----------------
        int rc = bid;
        int t = tid >> 3, ch = tid & 7;
        __shared__ float sc_[32][9];
        __shared__ float coff[8];
        __shared__ float gbuf[32];
        if (tid < 8) {
            float s = 0.f;
            const float* pp = partial + (size_t)b * 64 * 8 + tid;
            for (int c = 0; c < rc; c++) s += pp[c * 8];
            coff[tid] = s;
        }
        float* fp = fk + ((size_t)(b * L + rc * 32 + t)) * 40;
        float own = fp[32 + ch];
        sc_[t][ch] = own;
        __syncthreads();
        for (int off = 1; off < 32; off <<= 1) {
            float v = 0.f;
            if (t >= off) v = sc_[t - off][ch];
            __syncthreads();
            if (t >= off) sc_[t][ch] += v;
            __syncthreads();
        }
        float run = coff[ch] + sc_[t][ch] - own;
        __syncthreads();
        sc_[t][ch] = run;
        __syncthreads();
        if (tid < 32) {
            int tg = rc * 32 + tid;
            float r0 = sc_[tid][0], r1 = sc_[tid][1], r2 = sc_[tid][2], r3 = sc_[tid][3];
            float r4 = sc_[tid][4], r5 = sc_[tid][5], r6 = sc_[tid][6], r7 = sc_[tid][7];
            float rmag = 0.25f * (sqrtf(r0 * r0 + r1 * r1) + sqrtf(r2 * r2 + r3 * r3) +
                                  sqrtf(r4 * r4 + r5 * r5) + sqrtf(r6 * r6 + r7 * r7));
            float scv = fminf(fmaxf(resonance_scale[0], 1.f), 20.f);
            float thv = fminf(fmaxf(resonance_threshold[0], 0.1f), 0.9f);
            float nres = rmag / sqrtf(fmaxf((float)tg, 1.0f));
            float surprise = 0.5f * (1.0f - tanhf(scv * (nres - thv)));
            gbuf[tid] = 1.0f / (1.0f + expf(-(surprise_scale[0] * (surprise - 0.5f) + surprise_bias[0])));
        }
        __syncthreads();
        float gv = gbuf[t];
#pragma unroll
        for (int e = 0; e < 5; e++) fp[ch * 5 + e] *= gv;
    } else {
        // ---------------- ltm_z ----------------
        int s = bid - 64;
        __shared__ float xs[16][260], rms[16][260], rss[16][260];
        float a0 = 0.f, a1 = 0.f, a2 = 0.f, a3 = 0.f;
        float c0 = 0.f, c1 = 0.f, c2 = 0.f, c3 = 0.f;
        int sp = 0;
        for (; sp + 4 <= s; sp += 4) {
            a0 += Sx16[((size_t)(b * 128 + sp)) * D + tid];
            a1 += Sx16[((size_t)(b * 128 + sp + 1)) * D + tid];
            a2 += Sx16[((size_t)(b * 128 + sp + 2)) * D + tid];
            a3 += Sx16[((size_t)(b * 128 + sp + 3)) * D + tid];
            c0 += Sxx16[((size_t)(b * 128 + sp)) * D + tid];
            c1 += Sxx16[((size_t)(b * 128 + sp + 1)) * D + tid];
            c2 += Sxx16[((size_t)(b * 128 + sp + 2)) * D + tid];
            c3 += Sxx16[((size_t)(b * 128 + sp + 3)) * D + tid];
        }
        for (; sp < s; sp++) {
            a0 += Sx16[((size_t)(b * 128 + sp)) * D + tid];
            c0 += Sxx16[((size_t)(b * 128 + sp)) * D + tid];
        }
        float runx = (a0 + a1) + (a2 + a3), runxx = (c0 + c1) + (c2 + c3);
        for (int k = 0; k < 16; k++) {
            int tg = s * 16 + k;
            float xv = x[((size_t)(b * L + tg)) * D + tid];
            runx += xv; runxx += xv * xv;
            float n = (float)(tg + 1);
            float rm = runx / n;
            float rv = runxx / n - rm * rm;
            xs[k][tid] = xv; rms[k][tid] = rm;
            rss[k][tid] = sqrtf(fmaxf(rv, 1e-8f));
        }
        __syncthreads();
        int tl = tid & 15, p = tid >> 4;
        const float* W0 = Wt + p * 768;
        float u0 = 0.f, u1 = 0.f, u2 = 0.f;
#pragma unroll 4
        for (int j4 = 0; j4 < 64; j4++) {
            float4 xv = *(float4*)&xs[tl][j4 * 4];
            float4 wx = *(const float4*)(W0 + j4 * 4);
            float4 rv = *(float4*)&rms[tl][j4 * 4];
            float4 wr = *(const float4*)(W0 + 256 + j4 * 4);
            float4 sv = *(float4*)&rss[tl][j4 * 4];
            float4 wz = *(const float4*)(W0 + 512 + j4 * 4);
            u0 += xv.x * wx.x + xv.y * wx.y + xv.z * wx.z + xv.w * wx.w;
            u1 += rv.x * wr.x + rv.y * wr.y + rv.z * wr.z + rv.w * wr.w;
            u2 += sv.x * wz.x + sv.y * wz.y + sv.z * wz.z + sv.w * wz.w;
        }
        float z = tanhf(u0 + u1 + u2) * PI_F;
        float si, co; sincosf(z, &si, &co);
        int tg = s * 16 + tl;
        czsz[((size_t)(b * L + tg)) * 32 + p] = co;
        czsz[((size_t)(b * L + tg)) * 32 + 16 + p] = si;
    }
}

// ------------- half-chunk outer-product sums Sh[b,c,h,f,d] (32-t halves) --------
__global__ __launch_bounds__(256) void outer_sums_kernel(
    const float* __restrict__ V, const float* __restrict__ fk,
    const float* __restrict__ posci, float* __restrict__ Sh) {
    int g = blockIdx.x >> 1, h = blockIdx.x & 1;
    int c = blockIdx.y;
    int b = blockIdx.z;
    int tid = threadIdx.x;
    __shared__ float Fk[32][40];
    int F0 = g * 36;
#pragma unroll
    for (int e = 0; e < 2; e++) {
        int idx = e * 256 + tid;     // 288 f4 = 32 rows x 9
        if (idx < 288) {
            int r = idx / 9, c4 = idx - r * 9;
            int tg = c * T + h * 32 + r;
            float4 v;
            if (g == 0) v = *(const float4*)(fk + ((size_t)(b * L + tg)) * 40 + c4 * 4);
            else if (c4 == 0) v = *(const float4*)(fk + ((size_t)(b * L + tg)) * 40 + 36);
            else v = *(const float4*)(posci + tg * 32 + (c4 - 1) * 4);
            *(float4*)&Fk[r][c4 * 4] = v;
        }
    }
    __syncthreads();
    float acc[36];
#pragma unroll
    for (int f = 0; f < 36; f++) acc[f] = 0.f;
    for (int t = 0; t < 32; t++) {
        float v = V[((size_t)(b * L + c * T + h * 32 + t)) * D + tid];
#pragma unroll
        for (int f4 = 0; f4 < 9; f4++) {
            float4 fkv = *(float4*)&Fk[t][f4 * 4];
            acc[f4 * 4 + 0] += fkv.x * v;
            acc[f4 * 4 + 1] += fkv.y * v;
            acc[f4 * 4 + 2] += fkv.z * v;
            acc[f4 * 4 + 3] += fkv.w * v;
        }
    }
    for (int f = 0; f < 36; f++)
        Sh[((((size_t)(b * C + c)) * 2 + h) * F + F0 + f) * D + tid] = acc[f];
}

// ------- exclusive prefix over chunks, combining half-chunk sums ---------------
__global__ __launch_bounds__(256) void prefix_kernel(const float* __restrict__ Sh,
                                                     float* __restrict__ S) {
    int bf = blockIdx.x;
    int b = bf / F, f = bf % F;
    int d = threadIdx.x;
    float v0[C], v1[C];
#pragma unroll
    for (int c = 0; c < C; c++) {
        v0[c] = Sh[((((size_t)(b * C + c)) * 2 + 0) * F + f) * D + d];
        v1[c] = Sh[((((size_t)(b * C + c)) * 2 + 1) * F + f) * D + d];
    }
    float run = 0.f;
#pragma unroll
    for (int c = 0; c < C; c++) {
        S[(((size_t)(b * C + c)) * F + f) * D + d] = run;
        run += v0[c] + v1[c];
    }
}

// ---- intra fused w/ hprep, 512 threads: hn = LN((Fq·M + A·V + pers)/nrm)·g + b --
__global__ __launch_bounds__(512) void intra_kernel(
    const float* __restrict__ V, float* __restrict__ hn,
    const float* __restrict__ fk, const float* __restrict__ fq,
    const float* __restrict__ posci, const float* __restrict__ Mexc,
    const float* __restrict__ pos_weight, const float* __restrict__ czsz,
    const float* __restrict__ ltm_mem, const float* __restrict__ ltm_count,
    const float* __restrict__ ltm_weight, const float* __restrict__ ln_gamma,
    const float* __restrict__ ln_beta) {
    int tg = blockIdx.x, c = blockIdx.y, b = blockIdx.z;
    int tid = threadIdx.x;
    int t0 = tg * 16;
    __shared__ float smem[8384];
    float (*Fk)[76] = (float(*)[76])smem;              // 64*76 = 4864
    float (*Fq)[76] = (float(*)[76])(smem + 4864);     // 16*76 -> 6080
    float (*As)[68] = (float(*)[68])(smem + 6080);     // 16*68 -> 7168
    float (*cs)[33]  = (float(*)[33])(smem + 7168);    // 528 -> 7696
    float (*part1)[17] = (float(*)[17])(smem + 7696);  // 272 -> 7968
    float (*part2)[17] = (float(*)[17])(smem + 7968);  // 272 -> 8240
    float* mu   = smem + 8240;
    float* rsig = smem + 8256;
    float (*hb)[260] = (float(*)[260])smem;            // aliases Fk (4160 <= 4864)
    float posq = 0.5f / (1.0f + expf(-pos_weight[0]));
    // stage Fk: 64 rows x 18 f4 (10 from fk, 8 from posci)
#pragma unroll
    for (int e = 0; e < 3; e++) {
        int idx = e * 512 + tid;
        if (idx < 1152) {
            int r = idx / 18, c4 = idx - r * 18;
            int tgl = c * T + r;
            float4 v;
            if (c4 < 10) v = *(const float4*)(fk + ((size_t)(b * L + tgl)) * 40 + c4 * 4);
            else v = *(const float4*)(posci + tgl * 32 + (c4 - 10) * 4);
            *(float4*)&Fk[r][c4 * 4] = v;
        }
    }
    // stage Fq: 16 rows x 18 f4; pos part scaled by posq
    if (tid < 288) {
        int r = tid / 18, c4 = tid - r * 18;
        int tgl = c * T + t0 + r;
        float4 v;
        if (c4 < 10) v = *(const float4*)(fq + ((size_t)(b * L + tgl)) * 40 + c4 * 4);
        else {
            v = *(const float4*)(posci + tgl * 32 + (c4 - 10) * 4);
            v.x *= posq; v.y *= posq; v.z *= posq; v.w *= posq;
        }
        *(float4*)&Fq[r][c4 * 4] = v;
    }
    // stage czsz: 512 = 16 rows x 32
    {
        int t = tid >> 5, q = tid & 31;
        cs[t][q] = czsz[((size_t)(b * L + c * T + t0 + t)) * 32 + q];
    }
    __syncthreads();
    // A[r][k]: 16 x 64; thread handles k = kA and kA+32 for row r (computed ONCE)
    {
        int r = tid >> 5, kA = tid & 31;
        int tglob = t0 + r;
        float a0 = 0.f, a1 = 0.f;
#pragma unroll
        for (int f4 = 0; f4 < 18; f4++) {
            float4 q = *(float4*)&Fq[r][f4 * 4];
            float4 kv0 = *(float4*)&Fk[kA][f4 * 4];
            float4 kv1 = *(float4*)&Fk[kA + 32][f4 * 4];
            a0 += q.x * kv0.x + q.y * kv0.y + q.z * kv0.z + q.w * kv0.w;
            a1 += q.x * kv1.x + q.y * kv1.y + q.z * kv1.z + q.w * kv1.w;
        }
        As[r][kA] = (kA <= tglob) ? a0 : 0.f;
        As[r][kA + 32] = (kA + 32 <= tglob) ? a1 : 0.f;
    }
    __syncthreads();   // Fk retired; region may be reused as hb
    // main: thread owns column d = tid&255, rows r0..r0+7 (r0 = (tid>>8)*8)
    int d = tid & 255, half = tid >> 8;
    int r0 = half * 8;
    float acc[8];
#pragma unroll
    for (int i = 0; i < 8; i++) acc[i] = 0.f;
    const float* Mp = Mexc + (((size_t)(b * C + c)) * F) * D + d;
#pragma unroll 8
    for (int f = 0; f < F; f++) {
        float m = Mp[(size_t)f * D];
#pragma unroll
        for (int i = 0; i < 8; i++) acc[i] += Fq[r0 + i][f] * m;
    }
    const float* Vp = V + ((size_t)(b * L + c * T)) * D + d;
    int kmax = t0 + r0 + 8;        // causality: rows r0..r0+7 need k <= t0+r0+7
#pragma unroll 8
    for (int k = 0; k < kmax; k++) {
        float v = Vp[(size_t)k * D];
#pragma unroll
        for (int i = 0; i < 8; i++) acc[i] += As[r0 + i][k] * v;
    }
    // + LTM pers, /nrm
    float lsig = 1.f / (1.f + expf(-ltm_weight[0]));
    float pnorm = sqrtf(fmaxf(ltm_count[0], 1.f) * (float)LTMP);
    float lcoef = lsig / pnorm;
    float Mre[16], Mim[16];
#pragma unroll
    for (int p = 0; p < 16; p++) {
        Mre[p] = ltm_mem[(p * D + d) * 2];
        Mim[p] = ltm_mem[(p * D + d) * 2 + 1];
    }
#pragma unroll
    for (int i = 0; i < 8; i++) {
        int row = r0 + i;
        float pers = 0.f;
#pragma unroll
        for (int p = 0; p < 16; p++) pers += Mre[p] * cs[row][p] + Mim[p] * cs[row][16 + p];
        int tgl = c * T + t0 + row;
        acc[i] = (acc[i] + lcoef * pers) / (2.0f * sqrtf((float)(tgl + 1)));
    }
    __syncthreads();   // all As/Fq/cs reads done before hb overwrite of Fk region
#pragma unroll
    for (int i = 0; i < 8; i++) hb[r0 + i][d] = acc[i];
    __syncthreads();
    // LN stats (tid<256): row = tid&15, e = tid>>4; cols e+16k -> 2-way banks
    if (tid < 256) {
        int row = tid & 15, e = tid >> 4;
        float s1 = 0.f, s2 = 0.f;
#pragma unroll
        for (int k = 0; k < 16; k++) {
            float v = hb[row][e + 16 * k];
            s1 += v; s2 += v * v;
        }
        part1[row][e] = s1; part2[row][e] = s2;
    }
    __syncthreads();
    if (tid < 16) {
        float s1 = 0.f, s2 = 0.f;
#pragma unroll
        for (int e = 0; e < 16; e++) { s1 += part1[tid][e]; s2 += part2[tid][e]; }
        float m = s1 / 256.f;
        mu[tid] = m;
        rsig[tid] = rsqrtf(fmaxf(s2 / 256.f - m * m, 0.f) + 1e-5f);
    }
    __syncthreads();
    float gam = ln_gamma[d], bet = ln_beta[d];
#pragma unroll
    for (int i = 0; i < 8; i++) {
        int row = r0 + i;
        hn[((size_t)(b * L + c * T + t0 + row)) * D + d] =
            (acc[i] - mu[row]) * rsig[row] * gam + bet;
    }
}

// ---------------- gemm_out: out = x + hn @ w_out + b_out ------------------------
__global__ __launch_bounds__(256) void gemm_out_kernel(
    const float* __restrict__ hn, const float* __restrict__ w_out,
    const float* __restrict__ b_out, const float* __restrict__ x,
    float* __restrict__ out) {
    int cg = blockIdx.x;
    int rc = blockIdx.y;
    int b  = blockIdx.z;
    int row0 = rc * 64;
    int tid = threadIdx.x;
    __shared__ float hs[2][32][74];
    __shared__ float wo[2][32][68];
    int rg = tid >> 4, cgi = tid & 15;
    int r0 = rg * 4, c0 = cgi * 4;
    float acc[4][4];
#pragma unroll
    for (int i = 0; i < 4; i++)
#pragma unroll
        for (int e = 0; e < 4; e++) acc[i][e] = 0.f;
    int rrA = tid >> 3, k4A = tid & 7;
    int jA = tid >> 4, c4A = tid & 15;
    float4 hr0, hr1, wr0, wr1;

#define ISSUE_LOADS(kb_)                                                            \
    {                                                                               \
        hr0 = *(const float4*)(hn + ((size_t)(b * L + row0 + rrA)) * D + (kb_) + k4A * 4);      \
        hr1 = *(const float4*)(hn + ((size_t)(b * L + row0 + 32 + rrA)) * D + (kb_) + k4A * 4); \
        wr0 = *(const float4*)(w_out + (size_t)((kb_) + jA) * D + cg * 64 + c4A * 4);           \
        wr1 = *(const float4*)(w_out + (size_t)((kb_) + 16 + jA) * D + cg * 64 + c4A * 4);      \
    }
#define WRITE_LDS(bi)                                                               \
    {                                                                               \
        const float* hp0 = (const float*)&hr0;                                      \
        const float* hp1 = (const float*)&hr1;                                      \
        _Pragma("unroll")                                                           \
        for (int u = 0; u < 4; u++) {                                               \
            hs[bi][k4A * 4 + u][rrA] = hp0[u];                                      \
            hs[bi][k4A * 4 + u][32 + rrA] = hp1[u];                                 \
        }                                                                           \
        *(float4*)&wo[bi][jA][c4A * 4] = wr0;                                       \
        *(float4*)&wo[bi][16 + jA][c4A * 4] = wr1;                                  \
    }

    ISSUE_LOADS(0);
    WRITE_LDS(0);
    __syncthreads();
    for (int kc = 0; kc < 8; kc++) {
        if (kc < 7) ISSUE_LOADS((kc + 1) * 32);
        int bi = kc & 1;
#pragma unroll 8
        for (int j = 0; j < 32; j++) {
            float2 xlo = *(float2*)&hs[bi][j][r0];
            float2 xhi = *(float2*)&hs[bi][j][r0 + 2];
            float4 wv = *(float4*)&wo[bi][j][c0];
            acc[0][0] += xlo.x * wv.x; acc[0][1] += xlo.x * wv.y; acc[0][2] += xlo.x * wv.z; acc[0][3] += xlo.x * wv.w;
            acc[1][0] += xlo.y * wv.x; acc[1][1] += xlo.y * wv.y; acc[1][2] += xlo.y * wv.z; acc[1][3] += xlo.y * wv.w;
            acc[2][0] += xhi.x * wv.x; acc[2][1] += xhi.x * wv.y; acc[2][2] += xhi.x * wv.z; acc[2][3] += xhi.x * wv.w;
            acc[3][0] += xhi.y * wv.x; acc[3][1] += xhi.y * wv.y; acc[3][2] += xhi.y * wv.z; acc[3][3] += xhi.y * wv.w;
        }
        if (kc < 7) WRITE_LDS((kc + 1) & 1);
        __syncthreads();
    }
#undef ISSUE_LOADS
#undef WRITE_LDS
    {
        int d0 = cg * 64 + c0;
        float4 bo = *(const float4*)(b_out + d0);
#pragma unroll
        for (int i = 0; i < 4; i++) {
            size_t o = ((size_t)(b * L + row0 + r0 + i)) * D + d0;
            float4 xa = *(const float4*)(x + o);
            *(float4*)(out + o) = make_float4(xa.x + acc[i][0] + bo.x, xa.y + acc[i][1] + bo.y,
                                              xa.z + acc[i][2] + bo.z, xa.w + acc[i][3] + bo.w);
        }
    }
}

extern "C" void kernel_launch(void* const* d_in, const int* in_sizes, int n_in,
                              void* d_out, int out_size, void* d_ws, size_t ws_size,
                              hipStream_t stream) {
    (void)in_sizes; (void)n_in; (void)out_size; (void)ws_size;
    const float* x            = (const float*)d_in[0];
    const float* key_proj     = (const float*)d_in[1];
    const float* query_proj   = (const float*)d_in[2];
    const float* ltm_key_proj = (const float*)d_in[3];
    const float* pos_freqs    = (const float*)d_in[4];
    const float* w_value      = (const float*)d_in[5];
    const float* b_value      = (const float*)d_in[6];
    const float* ln_gamma     = (const float*)d_in[9];
    const float* ln_beta      = (const float*)d_in[10];
    const float* w_out        = (const float*)d_in[11];
    const float* b_out        = (const float*)d_in[12];
    const float* set_weights  = (const float*)d_in[13];
    const float* pos_weight   = (const float*)d_in[14];
    const float* surprise_scale      = (const float*)d_in[15];
    const float* surprise_bias       = (const float*)d_in[16];
    const float* resonance_scale     = (const float*)d_in[17];
    const float* resonance_threshold = (const float*)d_in[18];
    const float* ltm_weight   = (const float*)d_in[19];
    const float* ltm_mem      = (const float*)d_in[20];
    const float* ltm_count    = (const float*)d_in[21];
    float* out = (float*)d_out;

    float* ws = (float*)d_ws;
    size_t off = 0;
    float* V     = ws + off; off += (size_t)B * L * D;
    float* hn    = ws + off; off += (size_t)B * L * D;   // intra writes hn directly
    float* fk    = ws + off; off += (size_t)B * L * 40;
    float* fq    = ws + off; off += (size_t)B * L * 40;
    float* posci = ws + off; off += (size_t)L * 32;
    float* Sx16  = ws + off; off += (size_t)B * 128 * D;
    float* Sxx16 = ws + off; off += (size_t)B * 128 * D;
    float* czsz  = ws + off; off += (size_t)B * L * 32;
    float* Sh    = ws + off; off += (size_t)B * C * 2 * F * D;   // half-chunk sums
    float* S     = ws + off; off += (size_t)B * C * F * D;       // exclusive prefix
    float* Wt    = ws + off; off += (size_t)16 * 768;
    float* partial = ws + off; off += (size_t)B * 64 * 8;

    prep_kernel<<<dim3(688), 256, 0, stream>>>(pos_freqs, ltm_key_proj, x, posci, Wt,
                                               Sx16, Sxx16);
    featurize_kernel<<<dim3(4, 32, B), 256, 0, stream>>>(x, key_proj, query_proj, w_value,
                                                         b_value, set_weights, V, fk, fq, partial);
    mid_kernel<<<dim3(192, B), 256, 0, stream>>>(fk, partial, surprise_scale, surprise_bias,
                                                 resonance_scale, resonance_threshold,
                                                 x, Sx16, Sxx16, Wt, czsz);
    outer_sums_kernel<<<dim3(4, C, B), 256, 0, stream>>>(V, fk, posci, Sh);
    prefix_kernel<<<dim3(B * F), 256, 0, stream>>>(Sh, S);
    intra_kernel<<<dim3(4, C, B), 512, 0, stream>>>(V, hn, fk, fq, posci, S, pos_weight,
                                                    czsz, ltm_mem, ltm_count, ltm_weight,
                                                    ln_gamma, ln_beta);
    gemm_out_kernel<<<dim3(4, 32, B), 256, 0, stream>>>(hn, w_out, b_out, x, out);
}